// Round 12
// baseline (424.998 us; speedup 1.0000x reference)
//
#include <hip/hip_runtime.h>

#define TT  1024
#define DIN 8

// sigma(x) = 1 / (1 + exp2(-x*log2e))
__device__ __forceinline__ float fsig(float x) {
    float e = __builtin_amdgcn_exp2f(-1.4426950408889634f * x);
    return __builtin_amdgcn_rcpf(1.0f + e);
}
// tanh(x) = 2*sigma(2x) - 1
__device__ __forceinline__ float ftanh_(float x) {
    float e = __builtin_amdgcn_exp2f(-2.8853900817779268f * x);
    return 2.0f * __builtin_amdgcn_rcpf(1.0f + e) - 1.0f;
}
// DPP lane permute, compile-time ctrl.
// 0x141 = row_half_mirror (i <-> 7-i within 8) ; 0x1B = quad_perm(3,2,1,0)
// (i <-> 3-i within quad) ; 0xB1 = quad_perm(1,0,3,2) (pair swap).
template<int CTRL>
__device__ __forceinline__ float dppf(float v) {
    return __uint_as_float((unsigned)__builtin_amdgcn_update_dpp(
        0, (int)__float_as_uint(v), CTRL, 0xF, 0xF, true));
}
// 3-step mirror butterfly over an 8-lane group: after this, EVERY lane of the
// group holds the full 8-lane sum (verified: pairs {i,7-i}, then quad mirror,
// then pair swap covers all 8 distinct sources).
#define RED8(a)  { a += dppf<0x141>(a); a += dppf<0x1B>(a); a += dppf<0xB1>(a); }

// lgkm-only barrier: ds_writes visible + ds_reads of the old parity slot
// complete. Global stores (h2 scratch, never read by this kernel) and the
// scalar x prefetch stay in flight across it.
__device__ __forceinline__ void bar_lgkm() {
    asm volatile("s_waitcnt lgkmcnt(0)\n\ts_barrier" ::: "memory");
}

// ============================ kernel 1: recurrence ============================
// 8 waves / batch element. 8-lane group per hidden unit; group owns all 4 gate
// rows {i,f,g,o} of that unit. Lane s of a group reads ONE slice of the input:
//   L1 (waves 0-3): slice = 4 h1-floats (1 ds_read_b128) + x-col s (global
//                   scalar, 1-deep prefetch); 4 gates x 5 FMA.
//   L2 (waves 4-7): slice = 8 floats of the 64-wide [h2 | h1] concat
//                   (2 ds_read_b128); 4 gates x 8 FMA.
// 3-DPP mirror butterfly -> every lane has all 4 gate dots -> redundant cell
// update on all 8 lanes (identical values), lane s==0 publishes. DS reads/iter
// drop to 12 b128 (vs 32 in round-11) - the LDS queue-drain was the wall.
// Pipeline at iter t: L1 -> h1(t); L2 -> h2(t-1) (+scratch store). 1 barrier.
__global__ void __launch_bounds__(512, 2)
lstm_rec(const float* __restrict__ x,
         const float* __restrict__ Wih1, const float* __restrict__ Whh1,
         const float* __restrict__ bih1, const float* __restrict__ bhh1,
         const float* __restrict__ Wih2, const float* __restrict__ Whh2,
         const float* __restrict__ bih2, const float* __restrict__ bhh2,
         float* __restrict__ out)
{
    const int tid = threadIdx.x;
    const int wv  = tid >> 6;          // wave 0..7
    const int l   = tid & 63;
    const int s   = l & 7;             // slice lane within unit-group
    const int gi  = l >> 3;            // unit-group 0..7 within wave
    const int b   = blockIdx.x;
    const bool isL1 = (wv < 4);
    const int  wu   = isL1 ? wv : (wv - 4);
    const int  unit = wu*8 + gi;       // hidden unit 0..31

    __shared__ float hb1[2][32];       // h1 by parity
    __shared__ float hb2[2][32];       // h2 by parity
    if (tid < 64)       ((float*)hb1)[tid]      = 0.f;
    else if (tid < 128) ((float*)hb2)[tid - 64] = 0.f;

    // ---- per-lane weights: w[r*W + j] = gate r, slice col j ----
    float w[32];
    float bi, bf, bg, bo;
    if (isL1) {
#pragma unroll
        for (int r = 0; r < 4; ++r) {
            const int R = r*32 + unit;
#pragma unroll
            for (int j = 0; j < 4; ++j) w[r*4 + j] = Whh1[R*32 + s*4 + j];
            w[16 + r] = Wih1[R*DIN + s];
        }
        bi = bih1[unit]      + bhh1[unit];
        bf = bih1[32 + unit] + bhh1[32 + unit];
        bg = bih1[64 + unit] + bhh1[64 + unit];
        bo = bih1[96 + unit] + bhh1[96 + unit];
    } else {
        const float* Wb = (s < 4) ? Whh2 : Wih2;   // cols 0-31 = h2, 32-63 = h1
        const int co = (s & 3) * 8;
#pragma unroll
        for (int r = 0; r < 4; ++r) {
            const int R = r*32 + unit;
#pragma unroll
            for (int j = 0; j < 8; ++j) w[r*8 + j] = Wb[R*32 + co + j];
        }
        bi = bih2[unit]      + bhh2[unit];
        bf = bih2[32 + unit] + bhh2[32 + unit];
        bg = bih2[64 + unit] + bhh2[64 + unit];
        bo = bih2[96 + unit] + bhh2[96 + unit];
    }

    float c = 0.f;   // cell state, replicated identically across the 8 group lanes

    const float* __restrict__ xb = x   + (size_t)b * (TT*DIN);
    float* __restrict__ outb     = out + (size_t)b * (TT*80);

    float xcur = 0.f;
    if (isL1) xcur = xb[s];            // x(0)[s]
    int xoff = DIN + s;                // next x prefetch: x(1)[s]
    const int XMAX = (TT-1)*DIN + s;
    int o2 = 0;                        // running h2-scratch offset: (t-1)*80

    bar_lgkm();   // zero-init visible

#pragma unroll 1
    for (int t = 0; t <= TT; ++t) {
        const int p0  = t & 1;
        const int pm1 = p0 ^ 1;

        if (isL1) {
            if (t < TT) {
                float4 h4 = *reinterpret_cast<const float4*>(&hb1[pm1][s*4]);
                float ai = w[0] *h4.x + w[16]*xcur;
                float af = w[4] *h4.x + w[17]*xcur;
                float ag = w[8] *h4.x + w[18]*xcur;
                float ao = w[12]*h4.x + w[19]*xcur;
                ai += w[1]*h4.y;  af += w[5]*h4.y;  ag += w[9] *h4.y;  ao += w[13]*h4.y;
                ai += w[2]*h4.z;  af += w[6]*h4.z;  ag += w[10]*h4.z;  ao += w[14]*h4.z;
                ai += w[3]*h4.w;  af += w[7]*h4.w;  ag += w[11]*h4.w;  ao += w[15]*h4.w;
                // prefetch next x scalar (stays in flight across the barrier)
                xcur = xb[xoff];
                xoff = (xoff + DIN > XMAX) ? XMAX : (xoff + DIN);
                RED8(ai); RED8(af); RED8(ag); RED8(ao);
                float si = fsig(ai + bi);
                float sf = fsig(af + bf);
                float tg = ftanh_(ag + bg);
                float so = fsig(ao + bo);
                c = sf * c + si * tg;
                float hv = so * ftanh_(c);
                if (s == 0) hb1[p0][unit] = hv;     // publish h1(t)
            }
        } else {
            if (t >= 1) {
                const float* hin = (s < 4) ? &hb2[p0][(s & 3) * 8]
                                           : &hb1[pm1][(s & 3) * 8];
                float4 u0 = reinterpret_cast<const float4*>(hin)[0];
                float4 u1 = reinterpret_cast<const float4*>(hin)[1];
                float ai = w[0] *u0.x, af = w[8] *u0.x, ag = w[16]*u0.x, ao = w[24]*u0.x;
                ai += w[1]*u0.y;  af += w[9] *u0.y;  ag += w[17]*u0.y;  ao += w[25]*u0.y;
                ai += w[2]*u0.z;  af += w[10]*u0.z;  ag += w[18]*u0.z;  ao += w[26]*u0.z;
                ai += w[3]*u0.w;  af += w[11]*u0.w;  ag += w[19]*u0.w;  ao += w[27]*u0.w;
                ai += w[4]*u1.x;  af += w[12]*u1.x;  ag += w[20]*u1.x;  ao += w[28]*u1.x;
                ai += w[5]*u1.y;  af += w[13]*u1.y;  ag += w[21]*u1.y;  ao += w[29]*u1.y;
                ai += w[6]*u1.z;  af += w[14]*u1.z;  ag += w[22]*u1.z;  ao += w[30]*u1.z;
                ai += w[7]*u1.w;  af += w[15]*u1.w;  ag += w[23]*u1.w;  ao += w[31]*u1.w;
                RED8(ai); RED8(af); RED8(ag); RED8(ao);
                float si = fsig(ai + bi);
                float sf = fsig(af + bf);
                float tg = ftanh_(ag + bg);
                float so = fsig(ao + bo);
                c = sf * c + si * tg;
                float hv = so * ftanh_(c);
                if (s == 0) {
                    hb2[pm1][unit] = hv;            // publish h2(t-1)
                    outb[o2 + unit] = hv;           // scratch h2 for kernel 2
                }
                o2 += 80;
            }
        }

        bar_lgkm();
    }
}

// ============================ kernel 2: out linear ============================
// out[row][0:80] = h2[row] @ Wlin^T + blin, h2 scratch = out[row][0:32].
// Unchanged from round 11 (verified).
__global__ void __launch_bounds__(256, 4)
out_lin(const float* __restrict__ Wlin, const float* __restrict__ blin,
        float* __restrict__ out, int ntiles)
{
    __shared__ float wl[80][36];
    __shared__ float bl[80];
    __shared__ float ht[16][36];
    const int tid = threadIdx.x;

#pragma unroll 1
    for (int i = tid; i < 640; i += 256) {          // 80 rows x 8 float4
        const int cc = i >> 3, qq = i & 7;
        float4 v = reinterpret_cast<const float4*>(Wlin)[i];
        *reinterpret_cast<float4*>(&wl[cc][qq*4]) = v;
    }
    if (tid < 80) bl[tid] = blin[tid];
    __syncthreads();

    const int row = tid >> 4;   // 0..15
    const int cl  = tid & 15;   // 0..15

#pragma unroll 1
    for (int tile = blockIdx.x; tile < ntiles; tile += gridDim.x) {
        const size_t base = (size_t)tile * 16;
        if (tid < 128) {                            // stage 16 rows of h2
            const int r = tid >> 3, qq = tid & 7;
            float4 v = *reinterpret_cast<const float4*>(out + (base + r)*80 + qq*4);
            *reinterpret_cast<float4*>(&ht[r][qq*4]) = v;
        }
        __syncthreads();

        float hr[32];
#pragma unroll
        for (int j = 0; j < 8; ++j) {
            float4 v = *reinterpret_cast<const float4*>(&ht[row][j*4]);
            hr[4*j]=v.x; hr[4*j+1]=v.y; hr[4*j+2]=v.z; hr[4*j+3]=v.w;
        }
        float res[5];
#pragma unroll
        for (int cj = 0; cj < 5; ++cj) {
            const int cc = cl + 16*cj;
            float a0 = bl[cc], a1 = 0.f, a2 = 0.f, a3 = 0.f;
#pragma unroll
            for (int k = 0; k < 32; k += 4) {
                a0 += wl[cc][k]  *hr[k];   a1 += wl[cc][k+1]*hr[k+1];
                a2 += wl[cc][k+2]*hr[k+2]; a3 += wl[cc][k+3]*hr[k+3];
            }
            res[cj] = (a0 + a1) + (a2 + a3);
        }
        __syncthreads();   // ht reads complete before next tile's staging
#pragma unroll
        for (int cj = 0; cj < 5; ++cj)
            out[(base + row)*80 + cl + 16*cj] = res[cj];
    }
}

extern "C" void kernel_launch(void* const* d_in, const int* in_sizes, int n_in,
                              void* d_out, int out_size, void* d_ws, size_t ws_size,
                              hipStream_t stream) {
    const float* x    = (const float*)d_in[0];
    const float* Wih1 = (const float*)d_in[1];
    const float* Whh1 = (const float*)d_in[2];
    const float* bih1 = (const float*)d_in[3];
    const float* bhh1 = (const float*)d_in[4];
    const float* Wih2 = (const float*)d_in[5];
    const float* Whh2 = (const float*)d_in[6];
    const float* bih2 = (const float*)d_in[7];
    const float* bhh2 = (const float*)d_in[8];
    const float* Wlin = (const float*)d_in[9];
    const float* blin = (const float*)d_in[10];

    const int B = in_sizes[0] / (TT * DIN);   // 256
    const int ntiles = (B * TT) / 16;         // 16384

    hipLaunchKernelGGL(lstm_rec, dim3(B), dim3(512), 0, stream,
                       x, Wih1, Whh1, bih1, bhh1,
                       Wih2, Whh2, bih2, bhh2,
                       (float*)d_out);
    hipLaunchKernelGGL(out_lin, dim3(2048), dim3(256), 0, stream,
                       Wlin, blin, (float*)d_out, ntiles);
}